// Round 3
// baseline (269.035 us; speedup 1.0000x reference)
//
#include <hip/hip_runtime.h>
#include <hip/hip_bf16.h>

typedef __attribute__((ext_vector_type(4))) float f32x4;
typedef __attribute__((ext_vector_type(8))) short bf16x8;

#define MFMA16(a, b, c) __builtin_amdgcn_mfma_f32_16x16x32_bf16(a, b, c, 0, 0, 0)

#define AS1(p) ((const __attribute__((address_space(1))) void*)(p))
#define AS3(p) ((__attribute__((address_space(3))) void*)(p))

// XOR swizzle of 16B slot index within a 128B row
#define SWZ(r) ((((r) & 7)) ^ ((((r) >> 3) & 1) << 2))

__device__ __forceinline__ unsigned short f2bf(float f) {
  union { float f; unsigned u; } x; x.f = f;
  unsigned r = x.u + 0x7fffu + ((x.u >> 16) & 1u);  // RNE
  return (unsigned short)(r >> 16);
}

// ---------------- f32 -> bf16 conversion of x and the 4 weight matrices ----
__global__ __launch_bounds__(256) void convert_all(
    const float* __restrict__ x, const float* __restrict__ wq,
    const float* __restrict__ wk, const float* __restrict__ wv,
    const float* __restrict__ wo, unsigned short* __restrict__ dst) {
  const int NX = 4194304, NW = 1048576, TOT = NX + 4 * NW;
  for (int i = blockIdx.x * 256 + threadIdx.x; i < TOT; i += gridDim.x * 256) {
    float v;
    if (i < NX) {
      v = x[i];
    } else {
      int j = i - NX; int ws = j >> 20; int o = j & (NW - 1);
      v = (ws == 0) ? wq[o] : (ws == 1) ? wk[o] : (ws == 2) ? wv[o] : wo[o];
    }
    dst[i] = f2bf(v);
  }
}

// ---------------- int32 mask -> u8 (runs after gemm_qkv, into xb region) ---
__global__ __launch_bounds__(256) void convert_mask(
    const int* __restrict__ m, unsigned char* __restrict__ o) {
  const int i = blockIdx.x * 256 + threadIdx.x;  // * 4 elements
  const int4 v = ((const int4*)m)[i];
  uchar4 r;
  r.x = (unsigned char)v.x; r.y = (unsigned char)v.y;
  r.z = (unsigned char)v.z; r.w = (unsigned char)v.w;
  ((uchar4*)o)[i] = r;
}

// ---------------- shared 128x128 NT GEMM mainloop (C = A * W^T), K=1024 ----
__device__ __forceinline__ void gemm_nt_128(
    const unsigned short* __restrict__ A, const unsigned short* __restrict__ Bw,
    int m0, int n0, unsigned short* Al, unsigned short* Bl, f32x4 acc[4][4]) {
  const int t = threadIdx.x;
  const int l = t & 63;
  const int w = t >> 6, wr = w >> 1, wc = w & 1;
  const int lc = l & 15, lg = l >> 4;

  auto stage = [&](int buf, int kt) {
    const int k0 = kt * 32;
#pragma unroll
    for (int c = 0; c < 2; ++c) {
      const int e = (t + c * 256) * 8;
      const int row = e >> 5, col = e & 31;
      __builtin_amdgcn_global_load_lds(
          AS1(A + (size_t)(m0 + row) * 1024 + k0 + col),
          AS3(Al + buf * 4096 + (w * 64 + c * 256) * 8), 16, 0, 0);
      __builtin_amdgcn_global_load_lds(
          AS1(Bw + (size_t)(n0 + row) * 1024 + k0 + col),
          AS3(Bl + buf * 4096 + (w * 64 + c * 256) * 8), 16, 0, 0);
    }
  };

  stage(0, 0);
#pragma unroll 2
  for (int kt = 0; kt < 32; ++kt) {
    __syncthreads();
    if (kt + 1 < 32) stage((kt + 1) & 1, kt + 1);
    const unsigned short* Ab = Al + (kt & 1) * 4096;
    const unsigned short* Bb = Bl + (kt & 1) * 4096;
    bf16x8 af[4], bfr[4];
#pragma unroll
    for (int i = 0; i < 4; ++i)
      af[i] = *(const bf16x8*)(Ab + (wr * 64 + i * 16 + lc) * 32 + lg * 8);
#pragma unroll
    for (int j = 0; j < 4; ++j)
      bfr[j] = *(const bf16x8*)(Bb + (wc * 64 + j * 16 + lc) * 32 + lg * 8);
#pragma unroll
    for (int i = 0; i < 4; ++i)
#pragma unroll
      for (int j = 0; j < 4; ++j)
        acc[i][j] = MFMA16(af[i], bfr[j], acc[i][j]);
  }
}

// ---------------- QKV projection: Q,K -> (B,H,S,64); V -> (B,H,64,S) -------
__global__ __launch_bounds__(256) void gemm_qkv(
    const unsigned short* __restrict__ xb,
    const unsigned short* __restrict__ wqb, const unsigned short* __restrict__ wkb,
    const unsigned short* __restrict__ wvb,
    unsigned short* __restrict__ q, unsigned short* __restrict__ k,
    unsigned short* __restrict__ vt) {
  __shared__ unsigned short Al[2 * 4096], Bl[2 * 4096];
  const int z = blockIdx.z;
  const unsigned short* Bw = (z == 0) ? wqb : (z == 1) ? wkb : wvb;
  const int m0 = blockIdx.x * 128, n0 = blockIdx.y * 128;
  f32x4 acc[4][4] = {};
  gemm_nt_128(xb, Bw, m0, n0, Al, Bl, acc);

  const int l = threadIdx.x & 63, w = threadIdx.x >> 6;
  const int wr = w >> 1, wc = w & 1, lc = l & 15, lg = l >> 4;

  if (z == 2) {
    // V transposed: vt[bh][hd][s], 4 consecutive s packed into 8B store
#pragma unroll
    for (int i = 0; i < 4; ++i)
#pragma unroll
      for (int j = 0; j < 4; ++j) {
        const int m = m0 + wr * 64 + i * 16 + lg * 4;
        const int n = n0 + wc * 64 + j * 16 + lc;
        const int b = m >> 11, s = m & 2047, hh = n >> 6, hd = n & 63;
        ushort4 pk;
        pk.x = f2bf(acc[i][j][0]); pk.y = f2bf(acc[i][j][1]);
        pk.z = f2bf(acc[i][j][2]); pk.w = f2bf(acc[i][j][3]);
        *(ushort4*)(vt + (size_t)((b << 4) + hh) * 131072 + (size_t)hd * 2048 + s) = pk;
      }
  } else {
    unsigned short* C = (z == 0) ? q : k;
#pragma unroll
    for (int i = 0; i < 4; ++i)
#pragma unroll
      for (int j = 0; j < 4; ++j)
#pragma unroll
        for (int r = 0; r < 4; ++r) {
          const int m = m0 + wr * 64 + i * 16 + lg * 4 + r;
          const int n = n0 + wc * 64 + j * 16 + lc;
          const int b = m >> 11, s = m & 2047, hh = n >> 6, hd = n & 63;
          C[(size_t)((b << 4) + hh) * 131072 + s * 64 + hd] = f2bf(acc[i][j][r]);
        }
  }
}

// ---------------- output projection: out = ao @ Wo^T + bo  (f32 out) -------
__global__ __launch_bounds__(256) void gemm_out(
    const unsigned short* __restrict__ ao, const unsigned short* __restrict__ wob,
    const float* __restrict__ bias, float* __restrict__ out) {
  __shared__ unsigned short Al[2 * 4096], Bl[2 * 4096];
  const int m0 = blockIdx.x * 128, n0 = blockIdx.y * 128;
  f32x4 acc[4][4] = {};
  gemm_nt_128(ao, wob, m0, n0, Al, Bl, acc);

  const int l = threadIdx.x & 63, w = threadIdx.x >> 6;
  const int wr = w >> 1, wc = w & 1, lc = l & 15, lg = l >> 4;
#pragma unroll
  for (int i = 0; i < 4; ++i)
#pragma unroll
    for (int j = 0; j < 4; ++j)
#pragma unroll
      for (int r = 0; r < 4; ++r) {
        const int m = m0 + wr * 64 + i * 16 + lg * 4 + r;
        const int n = n0 + wc * 64 + j * 16 + lc;
        out[(size_t)m * 1024 + n] = acc[i][j][r] + bias[n];
      }
}

// ---------------- flash attention, max-free softmax, swapped QK^T ----------
// S^T = K.Q^T via mfma(K,Q): thread holds S[q=lane&15][kv=cb*16+lg*4+r].
// Mask: 4 dword loads/tile. P: 4 ds_write_b64/tile (cvt_pk packed).
__global__ __launch_bounds__(256, 4) void attn_fwd(
    const unsigned short* __restrict__ q, const unsigned short* __restrict__ k,
    const unsigned short* __restrict__ vt, const unsigned char* __restrict__ mb8,
    unsigned short* __restrict__ ao) {
  __shared__ unsigned short Kl[2][4096];   // [64 kv][64 d] swizzled
  __shared__ unsigned short Vl[2][4096];   // [64 d][64 kv] swizzled
  __shared__ unsigned short Pl[4][1024];   // per-wave [16 q][64 kv] swizzled
  // XCD-aware bijective swizzle: 1024 blocks, 8 XCDs, 128 consecutive per XCD
  const int orig = blockIdx.x;
  const int nid = (orig & 7) * 128 + (orig >> 3);
  const int bh = nid >> 5, b = bh >> 4;
  const int q0 = (nid & 31) * 64;
  const int t = threadIdx.x, l = t & 63, w = t >> 6;
  const int lc = l & 15, lg = l >> 4;

  // Q B-frags: col(q) = lc, k-elems(d) = h2*32 + lg*8 ..
  const unsigned short* qp = q + ((size_t)bh * 2048 + q0 + w * 16) * 64;
  bf16x8 qa[2];
  qa[0] = *(const bf16x8*)(qp + lc * 64 + lg * 8);
  qa[1] = *(const bf16x8*)(qp + lc * 64 + 32 + lg * 8);

  // ones B-frag (col 0 only) for row-sum accumulation on the MFMA pipe
  bf16x8 onesf;
#pragma unroll
  for (int j = 0; j < 8; ++j) ((unsigned short*)&onesf)[j] = (lc == 0) ? 0x3F80 : 0;

  const unsigned short* kp = k + (size_t)bh * 131072;
  const unsigned short* vp = vt + (size_t)bh * 131072;
  // per-thread mask row: q = q0 + w*16 + lc
  const unsigned char* mp = mb8 + (size_t)b * 4194304 + (size_t)(q0 + w * 16 + lc) * 2048;

  f32x4 oa[4] = {};
  f32x4 lsum = {};

  auto stage = [&](int buf, int kv0) {
#pragma unroll
    for (int c = 0; c < 2; ++c) {
      const int ldc = (c * 4 + w) * 64 + l;       // linear 16B-chunk idx 0..511
      const int row = ldc >> 3, ch = ldc & 7;
      const int sch = ch ^ SWZ(row);              // pre-swizzled global chunk
      __builtin_amdgcn_global_load_lds(
          AS1(kp + (size_t)(kv0 + row) * 64 + sch * 8),
          AS3(&Kl[buf][(c * 4 + w) * 512]), 16, 0, 0);
      __builtin_amdgcn_global_load_lds(
          AS1(vp + (size_t)row * 2048 + kv0 + sch * 8),
          AS3(&Vl[buf][(c * 4 + w) * 512]), 16, 0, 0);
    }
  };

  stage(0, 0);
  for (int tt = 0; tt < 32; ++tt) {
    const int kv0 = tt * 64;
    __syncthreads();                      // stage(tt) visible for all waves
    if (tt + 1 < 32) stage((tt + 1) & 1, kv0 + 64);
    const unsigned short* Kb = Kl[tt & 1];
    const unsigned short* Vb = Vl[tt & 1];

    // S^T accumulators initialized from mask bias (m==1 -> -2.4e5)
    f32x4 sa[4];
#pragma unroll
    for (int cb = 0; cb < 4; ++cb) {
      const unsigned mw = *(const unsigned*)(mp + kv0 + cb * 16 + lg * 4);
      sa[cb][0] = -240000.f * (float)(mw & 255u);
      sa[cb][1] = -240000.f * (float)((mw >> 8) & 255u);
      sa[cb][2] = -240000.f * (float)((mw >> 16) & 255u);
      sa[cb][3] = -240000.f * (float)(mw >> 24);
    }

    // S^T += K . Q^T   (A = K rows kv, B = Q cols q)
#pragma unroll
    for (int cb = 0; cb < 4; ++cb) {
      const int row = cb * 16 + lc;
#pragma unroll
      for (int h2 = 0; h2 < 2; ++h2) {
        bf16x8 kf = *(const bf16x8*)(Kb + row * 64 + ((h2 * 4 + lg) ^ SWZ(row)) * 8);
        sa[cb] = MFMA16(kf, qa[h2], sa[cb]);
      }
    }

    // P = exp2(S * 0.125*log2e) -> packed bf16 -> swizzled per-wave LDS
    unsigned short* Pw = (unsigned short*)Pl[w];
#pragma unroll
    for (int cb = 0; cb < 4; ++cb) {
      float2 ab, cd;
      ab.x = __builtin_amdgcn_exp2f(sa[cb][0] * 0.18033688f);
      ab.y = __builtin_amdgcn_exp2f(sa[cb][1] * 0.18033688f);
      cd.x = __builtin_amdgcn_exp2f(sa[cb][2] * 0.18033688f);
      cd.y = __builtin_amdgcn_exp2f(sa[cb][3] * 0.18033688f);
      __hip_bfloat162 lo = __float22bfloat162_rn(ab);
      __hip_bfloat162 hi = __float22bfloat162_rn(cd);
      uint2 pk;
      pk.x = *(unsigned*)&lo;
      pk.y = *(unsigned*)&hi;
      // global kv chunk g = cb*2 + (lg>>1); LDS slot = g ^ SWZ(q=lc); half = lg&1
      *(uint2*)(Pw + lc * 64 + ((cb * 2 + (lg >> 1)) ^ SWZ(lc)) * 8 + (lg & 1) * 4) = pk;
    }

    // O += P @ V ; lsum += P @ ones
#pragma unroll
    for (int kk = 0; kk < 2; ++kk) {
      bf16x8 pa = *(const bf16x8*)(Pw + lc * 64 + ((kk * 4 + lg) ^ SWZ(lc)) * 8);
      lsum = MFMA16(pa, onesf, lsum);
#pragma unroll
      for (int db = 0; db < 4; ++db) {
        const int d = db * 16 + lc;
        bf16x8 vf = *(const bf16x8*)(Vb + d * 64 + ((kk * 4 + lg) ^ SWZ(d)) * 8);
        oa[db] = MFMA16(pa, vf, oa[db]);
      }
    }
  }

  // broadcast row sums (col 0 lives in lane lg*16) and write (B,S,D) bf16
  float li[4];
#pragma unroll
  for (int r = 0; r < 4; ++r) li[r] = __shfl(lsum[r], l & 48, 64);
#pragma unroll
  for (int r = 0; r < 4; ++r) {
    const float inv = 1.0f / li[r];
    const int row = q0 + w * 16 + lg * 4 + r;
    unsigned short* dst = ao + ((size_t)b * 2048 + row) * 1024 + (bh & 15) * 64;
#pragma unroll
    for (int db = 0; db < 4; ++db) dst[db * 16 + lc] = f2bf(oa[db][r] * inv);
  }
}

extern "C" void kernel_launch(void* const* d_in, const int* in_sizes, int n_in,
                              void* d_out, int out_size, void* d_ws, size_t ws_size,
                              hipStream_t stream) {
  const float* x = (const float*)d_in[0];
  const int* mask = (const int*)d_in[1];
  const float* Wq = (const float*)d_in[2];
  const float* Wk = (const float*)d_in[3];
  const float* Wv = (const float*)d_in[4];
  const float* Wo = (const float*)d_in[5];
  const float* bo = (const float*)d_in[6];

  unsigned short* ws = (unsigned short*)d_ws;
  unsigned short* xb = ws;                   // 4194304 (B*S, D) bf16; later reused as u8 mask
  unsigned short* wqb = xb + 4194304;        // 1048576 each
  unsigned short* wkb = wqb + 1048576;
  unsigned short* wvb = wkb + 1048576;
  unsigned short* wob = wvb + 1048576;
  unsigned short* qb = wob + 1048576;        // (B,H,S,64) bf16
  unsigned short* kb = qb + 4194304;         // (B,H,S,64) bf16
  unsigned short* vtb = kb + 4194304;        // (B,H,64,S) bf16  (transposed V)
  unsigned short* aob = vtb + 4194304;       // (B*S, D) bf16

  unsigned char* mb8 = (unsigned char*)xb;   // 8.4MB u8 mask, reuses xb after gemm_qkv

  convert_all<<<dim3(4096), dim3(256), 0, stream>>>(x, Wq, Wk, Wv, Wo, ws);
  gemm_qkv<<<dim3(32, 8, 3), dim3(256), 0, stream>>>(xb, wqb, wkb, wvb, qb, kb, vtb);
  convert_mask<<<dim3(8192), dim3(256), 0, stream>>>(mask, mb8);
  attn_fwd<<<dim3(1024), dim3(256), 0, stream>>>(qb, kb, vtb, mb8, aob);
  gemm_out<<<dim3(32, 8), dim3(256), 0, stream>>>(aob, wob, bo, (float*)d_out);
}